// Round 8
// baseline (507.572 us; speedup 1.0000x reference)
//
#include <hip/hip_runtime.h>
#include <hip/hip_cooperative_groups.h>
#include <hip/hip_fp16.h>
#include <math.h>

namespace cg = cooperative_groups;

#define N_NODES 10000
#define E_IN    320000
#define E_TOT   330000   /* E_IN + N self loops */
#define H1      4
#define C       128
#define F1      512      /* H1*C */
#define GB      512      /* coop grid blocks (2 blocks/CU x 256 CUs) */

typedef _Float16 f16x8 __attribute__((ext_vector_type(8)));
typedef float    f32x4 __attribute__((ext_vector_type(4)));

// ================= cooperative frontend =================
// P0: deg zero + as1/ad1 (blocks 0..39) + W2 fp16 cvt (blocks 40..103)
// P1: hist | P2: distributed scan | P3: scatter | P4: fused layer-1
__global__ __launch_bounds__(256, 2) void k_build(
    const float* __restrict__ x, const int* __restrict__ srci, const int* __restrict__ dsti,
    const float* __restrict__ W1, const float* __restrict__ asw, const float* __restrict__ adw,
    const float* __restrict__ W2, _Float16* __restrict__ w2h,
    float4* __restrict__ as1v, float4* __restrict__ ad1v,
    int* __restrict__ deg, int* __restrict__ offs, int* __restrict__ cursor,
    int* __restrict__ scsr, int* __restrict__ exclg, int* __restrict__ bsum,
    float* __restrict__ wxn)
{
    cg::grid_group grid = cg::this_grid();
    __shared__ float red[4][8];
    __shared__ float prep_s[16];
    __shared__ int sc[256];
    int tid = threadIdx.x;
    int b = blockIdx.x;

    // ---------- P0 ----------
    if (b < 40) {
        int j = tid, j2 = tid + 256;
        float w0a = W1[j],  w1a = W1[F1 + j];
        float w0b = W1[j2], w1b = W1[F1 + j2];
        float aa = asw[j], dd = adw[j], ab = asw[j2], db = adw[j2];
        float q0 = w0a*aa, q1 = w1a*aa, q2 = w0a*dd, q3 = w1a*dd;
        float q4 = w0b*ab, q5 = w1b*ab, q6 = w0b*db, q7 = w1b*db;
        #pragma unroll
        for (int o = 32; o > 0; o >>= 1) {
            q0 += __shfl_down(q0, o); q1 += __shfl_down(q1, o);
            q2 += __shfl_down(q2, o); q3 += __shfl_down(q3, o);
            q4 += __shfl_down(q4, o); q5 += __shfl_down(q5, o);
            q6 += __shfl_down(q6, o); q7 += __shfl_down(q7, o);
        }
        int wave = tid >> 6, lane = tid & 63;
        if (lane == 0) {
            red[wave][0] = q0; red[wave][1] = q1; red[wave][2] = q2; red[wave][3] = q3;
            red[wave][4] = q4; red[wave][5] = q5; red[wave][6] = q6; red[wave][7] = q7;
        }
        __syncthreads();
        if (tid < 16) {
            int t = tid >> 2;
            int h = tid & 3;
            int w0 = (h & 1) * 2;
            int r  = t + (h >> 1) * 4;
            prep_s[t*4 + h] = red[w0][r] + red[w0+1][r];
        }
        __syncthreads();
        int n = b * 256 + tid;
        if (n < N_NODES) {
            deg[n] = 0;
            float x0 = x[2*n], x1 = x[2*n+1];
            float4 A0 = *(const float4*)(prep_s);
            float4 A1 = *(const float4*)(prep_s + 4);
            float4 D0 = *(const float4*)(prep_s + 8);
            float4 D1 = *(const float4*)(prep_s + 12);
            as1v[n] = make_float4(x0*A0.x + x1*A1.x, x0*A0.y + x1*A1.y,
                                  x0*A0.z + x1*A1.z, x0*A0.w + x1*A1.w);
            ad1v[n] = make_float4(x0*D0.x + x1*D1.x, x0*D0.y + x1*D1.y,
                                  x0*D0.z + x1*D1.z, x0*D0.w + x1*D1.w);
        }
    } else if (b < 104) {
        int t = (b - 40) * 256 + tid;     // < 16384, 4 elems each
        int e0 = t * 4;
        int c = e0 >> 9;
        int kk0 = e0 & 511;
        int xr = (c & 7) << 3;
        _Float16 o4[4];
        #pragma unroll
        for (int j = 0; j < 4; ++j) o4[j] = (_Float16)W2[((kk0 + j) ^ xr) * C + c];
        *(uint2*)(w2h + c * F1 + kk0) = *(uint2*)o4;
    }
    grid.sync();

    // ---------- P1: histogram ----------
    for (int t = b * 256 + tid; t < E_TOT; t += GB * 256) {
        int d = (t < E_IN) ? dsti[t] : (t - E_IN);
        atomicAdd(&deg[d], 1);
    }
    grid.sync();

    // ---------- P2a: per-block 256-wide scan ----------
    int n2 = b * 256 + tid;
    if (b < 40) {
        int v = (n2 < N_NODES) ? deg[n2] : 0;
        sc[tid] = v;
        __syncthreads();
        for (int o = 1; o < 256; o <<= 1) {
            int u = (tid >= o) ? sc[tid - o] : 0;
            __syncthreads();
            sc[tid] += u;
            __syncthreads();
        }
        if (n2 < N_NODES) exclg[n2] = sc[tid] - v;
        if (tid == 255) bsum[b] = sc[255];
    }
    grid.sync();

    // ---------- P2b: scan the 40 block sums ----------
    if (b == 0 && tid == 0) {
        int run = 0;
        for (int i = 0; i < 40; ++i) { int s = bsum[i]; bsum[i] = run; run += s; }
        offs[N_NODES] = run;   // == E_TOT
    }
    grid.sync();

    // ---------- P2c: write offs/cursor ----------
    if (b < 40 && n2 < N_NODES) {
        int o = bsum[b] + exclg[n2];
        offs[n2] = o;
        cursor[n2] = o;
    }
    grid.sync();

    // ---------- P3: scatter ----------
    for (int t = b * 256 + tid; t < E_TOT; t += GB * 256) {
        int d = (t < E_IN) ? dsti[t] : (t - E_IN);
        int s = (t < E_IN) ? srci[t] : (t - E_IN);
        int pos = atomicAdd(&cursor[d], 1);
        scsr[pos] = s;
    }
    grid.sync();

    // ---------- P4: fused layer-1 (16 lanes/node) ----------
    const float2* xv = (const float2*)x;
    int sub = tid & 15;
    for (int node = b * 16 + (tid >> 4); node < N_NODES; node += GB * 16) {
        int beg = offs[node], end = offs[node + 1];
        float4 ad = ad1v[node];
        float s0 = 0.f, s1 = 0.f, s2 = 0.f, s3 = 0.f;
        float w00 = 0.f, w01 = 0.f, w10 = 0.f, w11 = 0.f;
        float w20 = 0.f, w21 = 0.f, w30 = 0.f, w31 = 0.f;
        int i = beg + sub;
        if (i < end) {
            int s = scsr[i];
            for (;;) {
                float4 a = as1v[s];
                float2 xs = xv[s];
                int inext = i + 16;
                bool more = inext < end;
                int snext = 0;
                if (more) snext = scsr[inext];
                float e0 = a.x + ad.x; e0 = e0 > 0.f ? e0 : 0.2f*e0;
                float e1 = a.y + ad.y; e1 = e1 > 0.f ? e1 : 0.2f*e1;
                float e2 = a.z + ad.z; e2 = e2 > 0.f ? e2 : 0.2f*e2;
                float e3 = a.w + ad.w; e3 = e3 > 0.f ? e3 : 0.2f*e3;
                float p0 = __expf(e0), p1 = __expf(e1), p2 = __expf(e2), p3 = __expf(e3);
                s0 += p0; s1 += p1; s2 += p2; s3 += p3;
                w00 += p0*xs.x; w01 += p0*xs.y; w10 += p1*xs.x; w11 += p1*xs.y;
                w20 += p2*xs.x; w21 += p2*xs.y; w30 += p3*xs.x; w31 += p3*xs.y;
                if (!more) break;
                i = inext; s = snext;
            }
        }
        #pragma unroll
        for (int o = 1; o < 16; o <<= 1) {
            s0 += __shfl_xor(s0, o); s1 += __shfl_xor(s1, o);
            s2 += __shfl_xor(s2, o); s3 += __shfl_xor(s3, o);
            w00 += __shfl_xor(w00, o); w01 += __shfl_xor(w01, o);
            w10 += __shfl_xor(w10, o); w11 += __shfl_xor(w11, o);
            w20 += __shfl_xor(w20, o); w21 += __shfl_xor(w21, o);
            w30 += __shfl_xor(w30, o); w31 += __shfl_xor(w31, o);
        }
        if (sub == 0) {
            float i0 = 1.f/(s0 + 1e-16f), i1 = 1.f/(s1 + 1e-16f);
            float i2 = 1.f/(s2 + 1e-16f), i3 = 1.f/(s3 + 1e-16f);
            float4* W = (float4*)(wxn + node*8);
            W[0] = make_float4(w00*i0, w01*i0, w10*i1, w11*i1);
            W[1] = make_float4(w20*i2, w21*i2, w30*i3, w31*i3);
        }
    }
}

// ---------- layer-2 GEMM via fp16 MFMA + attn2 epilogue ----------
__global__ __launch_bounds__(256, 1) void k_gemm2(
    const float* __restrict__ wxn, const float* __restrict__ W1,
    const float* __restrict__ b1, const _Float16* __restrict__ w2h,
    const float* __restrict__ asw, const float* __restrict__ adw,
    __half* __restrict__ h2h, float* __restrict__ as2, float* __restrict__ ad2)
{
    __shared__ _Float16 w2t[F1 * C];     // 128 KiB: [c][k^xr]
    int tid = threadIdx.x;
    #pragma unroll
    for (int it = 0; it < 32; ++it) {
        int idx = (it * 256 + tid) * 8;
        *(f16x8*)(w2t + idx) = *(const f16x8*)(w2h + idx);
    }
    __syncthreads();

    int wid = tid >> 6, lane = tid & 63;
    int tile = blockIdx.x * 4 + wid;
    if (tile >= N_NODES / 16) return;
    int n0w = tile * 16;
    int col = lane & 15;
    int krow = (lane >> 4) * 8;
    int qr4 = (lane >> 4) * 4;
    int node = n0w + col;

    float4 wv0 = *(const float4*)(wxn + node * 8);
    float4 wv1 = *(const float4*)(wxn + node * 8 + 4);

    f32x4 acc[8];
    #pragma unroll
    for (int mt = 0; mt < 8; ++mt) acc[mt] = (f32x4){0.f, 0.f, 0.f, 0.f};

    int xr = (col & 7) << 3;
    const float* W1r0 = W1;
    const float* W1r1 = W1 + F1;

    #pragma unroll
    for (int h = 0; h < 4; ++h) {
        float wa = (h == 0) ? wv0.x : (h == 1) ? wv0.z : (h == 2) ? wv1.x : wv1.z;
        float wb = (h == 0) ? wv0.y : (h == 1) ? wv0.w : (h == 2) ? wv1.y : wv1.w;
        #pragma unroll
        for (int kq = 0; kq < 4; ++kq) {
            int kc = h * 4 + kq;
            int k0 = kc * 32 + krow;
            float4 a0 = *(const float4*)(W1r0 + k0);
            float4 a1 = *(const float4*)(W1r0 + k0 + 4);
            float4 c0 = *(const float4*)(W1r1 + k0);
            float4 c1 = *(const float4*)(W1r1 + k0 + 4);
            float4 b0 = *(const float4*)(b1 + k0);
            float4 b1v = *(const float4*)(b1 + k0 + 4);
            f16x8 bf;
            float v;
            v = wa*a0.x + wb*c0.x + b0.x;  bf[0] = (_Float16)(v > 0.f ? v : 0.f);
            v = wa*a0.y + wb*c0.y + b0.y;  bf[1] = (_Float16)(v > 0.f ? v : 0.f);
            v = wa*a0.z + wb*c0.z + b0.z;  bf[2] = (_Float16)(v > 0.f ? v : 0.f);
            v = wa*a0.w + wb*c0.w + b0.w;  bf[3] = (_Float16)(v > 0.f ? v : 0.f);
            v = wa*a1.x + wb*c1.x + b1v.x; bf[4] = (_Float16)(v > 0.f ? v : 0.f);
            v = wa*a1.y + wb*c1.y + b1v.y; bf[5] = (_Float16)(v > 0.f ? v : 0.f);
            v = wa*a1.z + wb*c1.z + b1v.z; bf[6] = (_Float16)(v > 0.f ? v : 0.f);
            v = wa*a1.w + wb*c1.w + b1v.w; bf[7] = (_Float16)(v > 0.f ? v : 0.f);
            int kbase = col * F1 + (k0 ^ xr);
            #pragma unroll
            for (int mt = 0; mt < 8; ++mt) {
                f16x8 af = *(const f16x8*)(&w2t[mt * 16 * F1 + kbase]);
                acc[mt] = __builtin_amdgcn_mfma_f32_16x16x32_f16(af, bf, acc[mt], 0, 0, 0);
            }
        }
    }

    float ps = 0.f, pd = 0.f;
    __half* hbase = h2h + (size_t)node * C + qr4;
    #pragma unroll
    for (int mt = 0; mt < 8; ++mt) {
        f32x4 a = acc[mt];
        __half2 lo = __floats2half2_rn(a[0], a[1]);
        __half2 hi = __floats2half2_rn(a[2], a[3]);
        uint2 u; u.x = *(uint*)&lo; u.y = *(uint*)&hi;
        *(uint2*)(hbase + mt * 16) = u;
        float4 av = *(const float4*)(asw + mt * 16 + qr4);
        float4 dv = *(const float4*)(adw + mt * 16 + qr4);
        ps += a[0]*av.x + a[1]*av.y + a[2]*av.z + a[3]*av.w;
        pd += a[0]*dv.x + a[1]*dv.y + a[2]*dv.z + a[3]*dv.w;
    }
    ps += __shfl_xor(ps, 16); ps += __shfl_xor(ps, 32);
    pd += __shfl_xor(pd, 16); pd += __shfl_xor(pd, 32);
    if (lane < 16) { as2[n0w + lane] = ps; ad2[n0w + lane] = pd; }
}

// ---------- layer-2: softmax + aggregation + bias/relu + projection ----------
__global__ __launch_bounds__(256) void k_agg2(
    const int* __restrict__ offs, const int* __restrict__ scsr,
    const float* __restrict__ as2, const float* __restrict__ ad2,
    const __half* __restrict__ h2h, const float* __restrict__ b2,
    const float* __restrict__ Wp, const float* __restrict__ bp,
    float* __restrict__ out)
{
    int n = blockIdx.x * 4 + (threadIdx.x >> 6);
    int lane = threadIdx.x & 63;
    int half = lane >> 5;
    int cl = lane & 31;
    int beg = offs[n], end = offs[n + 1];
    float adn = ad2[n];
    float a0 = 0.f, a1 = 0.f, a2 = 0.f, a3 = 0.f, psum = 0.f;
    int i = beg + half;
    for (; i + 6 < end; i += 8) {
        int s0 = scsr[i], s1 = scsr[i+2], s2 = scsr[i+4], s3 = scsr[i+6];
        float e0 = as2[s0] + adn, e1 = as2[s1] + adn;
        float e2 = as2[s2] + adn, e3 = as2[s3] + adn;
        uint2 q0 = *(const uint2*)(h2h + (size_t)s0*C + 4*cl);
        uint2 q1 = *(const uint2*)(h2h + (size_t)s1*C + 4*cl);
        uint2 q2 = *(const uint2*)(h2h + (size_t)s2*C + 4*cl);
        uint2 q3 = *(const uint2*)(h2h + (size_t)s3*C + 4*cl);
        e0 = e0 > 0.f ? e0 : 0.2f*e0;  float p0 = __expf(e0);
        e1 = e1 > 0.f ? e1 : 0.2f*e1;  float p1 = __expf(e1);
        e2 = e2 > 0.f ? e2 : 0.2f*e2;  float p2 = __expf(e2);
        e3 = e3 > 0.f ? e3 : 0.2f*e3;  float p3 = __expf(e3);
        psum += (p0 + p1) + (p2 + p3);
        float2 f0a = __half22float2(*(__half2*)&q0.x), f0b = __half22float2(*(__half2*)&q0.y);
        float2 f1a = __half22float2(*(__half2*)&q1.x), f1b = __half22float2(*(__half2*)&q1.y);
        float2 f2a = __half22float2(*(__half2*)&q2.x), f2b = __half22float2(*(__half2*)&q2.y);
        float2 f3a = __half22float2(*(__half2*)&q3.x), f3b = __half22float2(*(__half2*)&q3.y);
        a0 += p0*f0a.x + p1*f1a.x + p2*f2a.x + p3*f3a.x;
        a1 += p0*f0a.y + p1*f1a.y + p2*f2a.y + p3*f3a.y;
        a2 += p0*f0b.x + p1*f1b.x + p2*f2b.x + p3*f3b.x;
        a3 += p0*f0b.y + p1*f1b.y + p2*f2b.y + p3*f3b.y;
    }
    for (; i < end; i += 2) {
        int s = scsr[i];
        float e = as2[s] + adn; e = e > 0.f ? e : 0.2f*e;
        float p = __expf(e);
        psum += p;
        uint2 q = *(const uint2*)(h2h + (size_t)s*C + 4*cl);
        float2 fa = __half22float2(*(__half2*)&q.x), fb = __half22float2(*(__half2*)&q.y);
        a0 += p*fa.x; a1 += p*fa.y; a2 += p*fb.x; a3 += p*fb.y;
    }
    a0 += __shfl_xor(a0, 32); a1 += __shfl_xor(a1, 32);
    a2 += __shfl_xor(a2, 32); a3 += __shfl_xor(a3, 32);
    psum += __shfl_xor(psum, 32);
    float inv = 1.f / (psum + 1e-16f);
    float4 bb = *(const float4*)(b2 + 4*cl);
    float4 wp = *(const float4*)(Wp + 4*cl);
    float v0 = a0*inv + bb.x; v0 = v0 > 0.f ? v0 : 0.f;
    float v1 = a1*inv + bb.y; v1 = v1 > 0.f ? v1 : 0.f;
    float v2 = a2*inv + bb.z; v2 = v2 > 0.f ? v2 : 0.f;
    float v3 = a3*inv + bb.w; v3 = v3 > 0.f ? v3 : 0.f;
    float contrib = v0*wp.x + v1*wp.y + v2*wp.z + v3*wp.w;
    #pragma unroll
    for (int o = 1; o < 32; o <<= 1) contrib += __shfl_xor(contrib, o);
    if (lane == 0) out[n] = contrib + bp[0];
}

// ---------------- host launcher ----------------
extern "C" void kernel_launch(void* const* d_in, const int* in_sizes, int n_in,
                              void* d_out, int out_size, void* d_ws, size_t ws_size,
                              hipStream_t stream)
{
    const float* x    = (const float*)d_in[0];
    const int*   ei   = (const int*)d_in[1];
    const int*   srci = ei;
    const int*   dsti = ei + E_IN;
    const float* W1   = (const float*)d_in[2];
    const float* as1w = (const float*)d_in[3];
    const float* ad1w = (const float*)d_in[4];
    const float* b1   = (const float*)d_in[5];
    const float* W2   = (const float*)d_in[6];
    const float* as2w = (const float*)d_in[7];
    const float* ad2w = (const float*)d_in[8];
    const float* b2   = (const float*)d_in[9];
    const float* Wp   = (const float*)d_in[10];
    const float* bp   = (const float*)d_in[11];
    float* out = (float*)d_out;

    char* ws = (char*)d_ws;
    size_t off = 0;
    auto alloc = [&](size_t bytes) -> char* {
        char* p = ws + off;
        off = (off + bytes + 255) & ~(size_t)255;
        return p;
    };
    float4*    as1v   = (float4*)alloc((size_t)N_NODES * 16);
    float4*    ad1v   = (float4*)alloc((size_t)N_NODES * 16);
    float*     wxn    = (float*)alloc((size_t)N_NODES * 8 * 4);
    __half*    h2h    = (__half*)alloc((size_t)N_NODES * C * 2);
    _Float16*  w2h    = (_Float16*)alloc((size_t)F1 * C * 2);
    float*     as2    = (float*)alloc((size_t)N_NODES * 4);
    float*     ad2    = (float*)alloc((size_t)N_NODES * 4);
    int*       deg    = (int*)alloc((size_t)N_NODES * 4);
    int*       offs   = (int*)alloc((size_t)(N_NODES + 1) * 4);
    int*       cursor = (int*)alloc((size_t)N_NODES * 4);
    int*       scsr   = (int*)alloc((size_t)E_TOT * 4);
    int*       exclg  = (int*)alloc((size_t)N_NODES * 4);
    int*       bsum   = (int*)alloc(64 * 4);

    void* kargs[] = {
        (void*)&x, (void*)&srci, (void*)&dsti,
        (void*)&W1, (void*)&as1w, (void*)&ad1w,
        (void*)&W2, (void*)&w2h,
        (void*)&as1v, (void*)&ad1v,
        (void*)&deg, (void*)&offs, (void*)&cursor,
        (void*)&scsr, (void*)&exclg, (void*)&bsum,
        (void*)&wxn
    };
    hipLaunchCooperativeKernel((void*)k_build, dim3(GB), dim3(256), kargs, 0, stream);

    k_gemm2<<<(N_NODES/16 + 3) / 4, 256, 0, stream>>>(wxn, W1, b1, w2h, as2w, ad2w,
                                                      h2h, as2, ad2);
    k_agg2<<<N_NODES / 4, 256, 0, stream>>>(offs, scsr, as2, ad2, h2h, b2, Wp, bp, out);
}

// Round 9
// 178.634 us; speedup vs baseline: 2.8414x; 2.8414x over previous
//
#include <hip/hip_runtime.h>
#include <hip/hip_fp16.h>
#include <math.h>

#define N_NODES 10000
#define E_IN    320000
#define E_TOT   330000   /* E_IN + N self loops */
#define H1      4
#define C       128
#define F1      512      /* H1*C */

typedef _Float16 f16x8 __attribute__((ext_vector_type(8)));
typedef float    f32x4 __attribute__((ext_vector_type(4)));

// ---------- fused frontend: blocks 0-39 = as1/ad1 + a1x pack + deg zero;
//            blocks 40-103 = W2 f32->fp16 transpose+swizzle ----------
__global__ __launch_bounds__(256) void k_as1z(
    const float* __restrict__ x, const float* __restrict__ W1,
    const float* __restrict__ asw, const float* __restrict__ adw,
    const float* __restrict__ W2, _Float16* __restrict__ w2h,
    float* __restrict__ a1x, float4* __restrict__ ad1v, int* __restrict__ deg)
{
    int tid = threadIdx.x;
    int b = blockIdx.x;
    if (b >= 40) {
        // ---- W2 convert: w2h[c*F1 + (k^xr)] = (fp16)W2[k*C+c] ----
        int t = (b - 40) * 256 + tid;     // < 16384, 4 elems each
        int e0 = t * 4;
        int c = e0 >> 9;
        int kk0 = e0 & 511;
        int xr = (c & 7) << 3;
        _Float16 o4[4];
        #pragma unroll
        for (int j = 0; j < 4; ++j) o4[j] = (_Float16)W2[((kk0 + j) ^ xr) * C + c];
        *(uint2*)(w2h + c * F1 + kk0) = *(uint2*)o4;
        return;
    }
    __shared__ float red[4][8];
    __shared__ float prep_s[16];   // A0[4] A1[4] D0[4] D1[4]
    {
        int j = tid, j2 = tid + 256;
        float w0a = W1[j],  w1a = W1[F1 + j];
        float w0b = W1[j2], w1b = W1[F1 + j2];
        float aa = asw[j], dd = adw[j], ab = asw[j2], db = adw[j2];
        float q0 = w0a*aa, q1 = w1a*aa, q2 = w0a*dd, q3 = w1a*dd;
        float q4 = w0b*ab, q5 = w1b*ab, q6 = w0b*db, q7 = w1b*db;
        #pragma unroll
        for (int o = 32; o > 0; o >>= 1) {
            q0 += __shfl_down(q0, o); q1 += __shfl_down(q1, o);
            q2 += __shfl_down(q2, o); q3 += __shfl_down(q3, o);
            q4 += __shfl_down(q4, o); q5 += __shfl_down(q5, o);
            q6 += __shfl_down(q6, o); q7 += __shfl_down(q7, o);
        }
        int wave = tid >> 6, lane = tid & 63;
        if (lane == 0) {
            red[wave][0] = q0; red[wave][1] = q1; red[wave][2] = q2; red[wave][3] = q3;
            red[wave][4] = q4; red[wave][5] = q5; red[wave][6] = q6; red[wave][7] = q7;
        }
        __syncthreads();
        if (tid < 16) {
            int t = tid >> 2;
            int h = tid & 3;
            int w0 = (h & 1) * 2;
            int r  = t + (h >> 1) * 4;
            prep_s[t*4 + h] = red[w0][r] + red[w0+1][r];
        }
        __syncthreads();
    }
    int n = b * 256 + tid;
    if (n >= N_NODES) return;
    deg[n] = 0;
    float x0 = x[2*n], x1 = x[2*n+1];
    float4 A0 = *(const float4*)(prep_s);
    float4 A1 = *(const float4*)(prep_s + 4);
    float4 D0 = *(const float4*)(prep_s + 8);
    float4 D1 = *(const float4*)(prep_s + 12);
    float4* A = (float4*)(a1x + n * 8);
    A[0] = make_float4(x0*A0.x + x1*A1.x, x0*A0.y + x1*A1.y,
                       x0*A0.z + x1*A1.z, x0*A0.w + x1*A1.w);
    A[1] = make_float4(x0, x1, 0.f, 0.f);
    ad1v[n] = make_float4(x0*D0.x + x1*D1.x, x0*D0.y + x1*D1.y,
                          x0*D0.z + x1*D1.z, x0*D0.w + x1*D1.w);
}

// ---------------- CSR build ----------------
__global__ void k_hist(const int* __restrict__ dsti, int* __restrict__ deg) {
    int t = blockIdx.x * blockDim.x + threadIdx.x;
    if (t >= E_TOT) return;
    int d = (t < E_IN) ? dsti[t] : (t - E_IN);
    atomicAdd(&deg[d], 1);
}

// single block, coalesced: stage 10000 degrees in LDS, scan there, write back
__global__ __launch_bounds__(256) void k_scan(
    const int* __restrict__ deg, int* __restrict__ offs, int* __restrict__ cursor)
{
    __shared__ int lds[10240];     // 40 KiB
    __shared__ int sc[256];
    int tid = threadIdx.x;
    for (int i = tid; i < 10240; i += 256) lds[i] = (i < N_NODES) ? deg[i] : 0;
    __syncthreads();
    const int CH = 40;
    int base = tid * CH;
    int sum = 0;
    #pragma unroll 8
    for (int j = 0; j < CH; ++j) {     // in-place exclusive scan of the chunk
        int v = lds[base + j];
        lds[base + j] = sum;
        sum += v;
    }
    sc[tid] = sum;
    __syncthreads();
    for (int o = 1; o < 256; o <<= 1) {
        int u = (tid >= o) ? sc[tid - o] : 0;
        __syncthreads();
        sc[tid] += u;
        __syncthreads();
    }
    int chunk_off = (tid == 0) ? 0 : sc[tid - 1];
    #pragma unroll 8
    for (int j = 0; j < CH; ++j) {
        int idx = base + j;
        if (idx < N_NODES) {
            int o = lds[idx] + chunk_off;
            offs[idx] = o;
            cursor[idx] = o;
        }
    }
    if (tid == 255) offs[N_NODES] = sc[255];   // == E_TOT
}

__global__ void k_scatter(const int* __restrict__ srci, const int* __restrict__ dsti,
                          int* __restrict__ cursor, int* __restrict__ scsr) {
    int t = blockIdx.x * blockDim.x + threadIdx.x;
    if (t >= E_TOT) return;
    int d = (t < E_IN) ? dsti[t] : (t - E_IN);
    int s = (t < E_IN) ? srci[t] : (t - E_IN);
    int pos = atomicAdd(&cursor[d], 1);
    scsr[pos] = s;
}

// ---------- layer-1 fused: scores + softmax (no max) + 2-dim aggregation ----------
// 16 lanes per node; single packed 32B gather per edge; pipelined scsr prefetch
__global__ __launch_bounds__(256) void k_fused1(
    const int* __restrict__ offs, const int* __restrict__ scsr,
    const float* __restrict__ a1x, const float4* __restrict__ ad1v,
    float* __restrict__ wxn)
{
    int node = blockIdx.x * 16 + (threadIdx.x >> 4);
    int sub = threadIdx.x & 15;
    int beg = offs[node], end = offs[node + 1];
    float4 ad = ad1v[node];
    float s0 = 0.f, s1 = 0.f, s2 = 0.f, s3 = 0.f;
    float w00 = 0.f, w01 = 0.f, w10 = 0.f, w11 = 0.f;
    float w20 = 0.f, w21 = 0.f, w30 = 0.f, w31 = 0.f;
    int i = beg + sub;
    if (i < end) {
        int s = scsr[i];
        for (;;) {
            float4 a  = *(const float4*)(a1x + s * 8);
            float2 xs = *(const float2*)(a1x + s * 8 + 4);
            int inext = i + 16;
            bool more = inext < end;
            int snext = 0;
            if (more) snext = scsr[inext];
            float e0 = a.x + ad.x; e0 = e0 > 0.f ? e0 : 0.2f*e0;
            float e1 = a.y + ad.y; e1 = e1 > 0.f ? e1 : 0.2f*e1;
            float e2 = a.z + ad.z; e2 = e2 > 0.f ? e2 : 0.2f*e2;
            float e3 = a.w + ad.w; e3 = e3 > 0.f ? e3 : 0.2f*e3;
            float p0 = __expf(e0), p1 = __expf(e1), p2 = __expf(e2), p3 = __expf(e3);
            s0 += p0; s1 += p1; s2 += p2; s3 += p3;
            w00 += p0*xs.x; w01 += p0*xs.y; w10 += p1*xs.x; w11 += p1*xs.y;
            w20 += p2*xs.x; w21 += p2*xs.y; w30 += p3*xs.x; w31 += p3*xs.y;
            if (!more) break;
            i = inext; s = snext;
        }
    }
    #pragma unroll
    for (int o = 1; o < 16; o <<= 1) {
        s0 += __shfl_xor(s0, o); s1 += __shfl_xor(s1, o);
        s2 += __shfl_xor(s2, o); s3 += __shfl_xor(s3, o);
        w00 += __shfl_xor(w00, o); w01 += __shfl_xor(w01, o);
        w10 += __shfl_xor(w10, o); w11 += __shfl_xor(w11, o);
        w20 += __shfl_xor(w20, o); w21 += __shfl_xor(w21, o);
        w30 += __shfl_xor(w30, o); w31 += __shfl_xor(w31, o);
    }
    if (sub == 0) {
        float i0 = 1.f/(s0 + 1e-16f), i1 = 1.f/(s1 + 1e-16f);
        float i2 = 1.f/(s2 + 1e-16f), i3 = 1.f/(s3 + 1e-16f);
        float4* W = (float4*)(wxn + node*8);
        W[0] = make_float4(w00*i0, w01*i0, w10*i1, w11*i1);
        W[1] = make_float4(w20*i2, w21*i2, w30*i3, w31*i3);
    }
}

// ---------- layer-2 GEMM via fp16 MFMA + attn2 epilogue ----------
__global__ __launch_bounds__(256, 1) void k_gemm2(
    const float* __restrict__ wxn, const float* __restrict__ W1,
    const float* __restrict__ b1, const _Float16* __restrict__ w2h,
    const float* __restrict__ asw, const float* __restrict__ adw,
    __half* __restrict__ h2h, float* __restrict__ as2, float* __restrict__ ad2)
{
    __shared__ _Float16 w2t[F1 * C];     // 128 KiB: [c][k^xr]
    int tid = threadIdx.x;
    #pragma unroll
    for (int it = 0; it < 32; ++it) {
        int idx = (it * 256 + tid) * 8;
        *(f16x8*)(w2t + idx) = *(const f16x8*)(w2h + idx);
    }
    __syncthreads();

    int wid = tid >> 6, lane = tid & 63;
    int tile = blockIdx.x * 4 + wid;
    if (tile >= N_NODES / 16) return;
    int n0w = tile * 16;
    int col = lane & 15;
    int krow = (lane >> 4) * 8;
    int qr4 = (lane >> 4) * 4;
    int node = n0w + col;

    float4 wv0 = *(const float4*)(wxn + node * 8);
    float4 wv1 = *(const float4*)(wxn + node * 8 + 4);

    f32x4 acc[8];
    #pragma unroll
    for (int mt = 0; mt < 8; ++mt) acc[mt] = (f32x4){0.f, 0.f, 0.f, 0.f};

    int xr = (col & 7) << 3;
    const float* W1r0 = W1;
    const float* W1r1 = W1 + F1;

    #pragma unroll
    for (int h = 0; h < 4; ++h) {
        float wa = (h == 0) ? wv0.x : (h == 1) ? wv0.z : (h == 2) ? wv1.x : wv1.z;
        float wb = (h == 0) ? wv0.y : (h == 1) ? wv0.w : (h == 2) ? wv1.y : wv1.w;
        #pragma unroll
        for (int kq = 0; kq < 4; ++kq) {
            int kc = h * 4 + kq;
            int k0 = kc * 32 + krow;
            float4 a0 = *(const float4*)(W1r0 + k0);
            float4 a1 = *(const float4*)(W1r0 + k0 + 4);
            float4 c0 = *(const float4*)(W1r1 + k0);
            float4 c1 = *(const float4*)(W1r1 + k0 + 4);
            float4 b0 = *(const float4*)(b1 + k0);
            float4 b1v = *(const float4*)(b1 + k0 + 4);
            f16x8 bf;
            float v;
            v = wa*a0.x + wb*c0.x + b0.x;  bf[0] = (_Float16)(v > 0.f ? v : 0.f);
            v = wa*a0.y + wb*c0.y + b0.y;  bf[1] = (_Float16)(v > 0.f ? v : 0.f);
            v = wa*a0.z + wb*c0.z + b0.z;  bf[2] = (_Float16)(v > 0.f ? v : 0.f);
            v = wa*a0.w + wb*c0.w + b0.w;  bf[3] = (_Float16)(v > 0.f ? v : 0.f);
            v = wa*a1.x + wb*c1.x + b1v.x; bf[4] = (_Float16)(v > 0.f ? v : 0.f);
            v = wa*a1.y + wb*c1.y + b1v.y; bf[5] = (_Float16)(v > 0.f ? v : 0.f);
            v = wa*a1.z + wb*c1.z + b1v.z; bf[6] = (_Float16)(v > 0.f ? v : 0.f);
            v = wa*a1.w + wb*c1.w + b1v.w; bf[7] = (_Float16)(v > 0.f ? v : 0.f);
            int kbase = col * F1 + (k0 ^ xr);
            #pragma unroll
            for (int mt = 0; mt < 8; ++mt) {
                f16x8 af = *(const f16x8*)(&w2t[mt * 16 * F1 + kbase]);
                acc[mt] = __builtin_amdgcn_mfma_f32_16x16x32_f16(af, bf, acc[mt], 0, 0, 0);
            }
        }
    }

    float ps = 0.f, pd = 0.f;
    __half* hbase = h2h + (size_t)node * C + qr4;
    #pragma unroll
    for (int mt = 0; mt < 8; ++mt) {
        f32x4 a = acc[mt];
        __half2 lo = __floats2half2_rn(a[0], a[1]);
        __half2 hi = __floats2half2_rn(a[2], a[3]);
        uint2 u; u.x = *(uint*)&lo; u.y = *(uint*)&hi;
        *(uint2*)(hbase + mt * 16) = u;
        float4 av = *(const float4*)(asw + mt * 16 + qr4);
        float4 dv = *(const float4*)(adw + mt * 16 + qr4);
        ps += a[0]*av.x + a[1]*av.y + a[2]*av.z + a[3]*av.w;
        pd += a[0]*dv.x + a[1]*dv.y + a[2]*dv.z + a[3]*dv.w;
    }
    ps += __shfl_xor(ps, 16); ps += __shfl_xor(ps, 32);
    pd += __shfl_xor(pd, 16); pd += __shfl_xor(pd, 32);
    if (lane < 16) { as2[n0w + lane] = ps; ad2[n0w + lane] = pd; }
}

// ---------- layer-2: softmax + aggregation + bias/relu + projection ----------
__global__ __launch_bounds__(256) void k_agg2(
    const int* __restrict__ offs, const int* __restrict__ scsr,
    const float* __restrict__ as2, const float* __restrict__ ad2,
    const __half* __restrict__ h2h, const float* __restrict__ b2,
    const float* __restrict__ Wp, const float* __restrict__ bp,
    float* __restrict__ out)
{
    int n = blockIdx.x * 4 + (threadIdx.x >> 6);
    int lane = threadIdx.x & 63;
    int half = lane >> 5;
    int cl = lane & 31;
    int beg = offs[n], end = offs[n + 1];
    float adn = ad2[n];
    float a0 = 0.f, a1 = 0.f, a2 = 0.f, a3 = 0.f, psum = 0.f;
    int i = beg + half;
    for (; i + 6 < end; i += 8) {
        int s0 = scsr[i], s1 = scsr[i+2], s2 = scsr[i+4], s3 = scsr[i+6];
        float e0 = as2[s0] + adn, e1 = as2[s1] + adn;
        float e2 = as2[s2] + adn, e3 = as2[s3] + adn;
        uint2 q0 = *(const uint2*)(h2h + (size_t)s0*C + 4*cl);
        uint2 q1 = *(const uint2*)(h2h + (size_t)s1*C + 4*cl);
        uint2 q2 = *(const uint2*)(h2h + (size_t)s2*C + 4*cl);
        uint2 q3 = *(const uint2*)(h2h + (size_t)s3*C + 4*cl);
        e0 = e0 > 0.f ? e0 : 0.2f*e0;  float p0 = __expf(e0);
        e1 = e1 > 0.f ? e1 : 0.2f*e1;  float p1 = __expf(e1);
        e2 = e2 > 0.f ? e2 : 0.2f*e2;  float p2 = __expf(e2);
        e3 = e3 > 0.f ? e3 : 0.2f*e3;  float p3 = __expf(e3);
        psum += (p0 + p1) + (p2 + p3);
        float2 f0a = __half22float2(*(__half2*)&q0.x), f0b = __half22float2(*(__half2*)&q0.y);
        float2 f1a = __half22float2(*(__half2*)&q1.x), f1b = __half22float2(*(__half2*)&q1.y);
        float2 f2a = __half22float2(*(__half2*)&q2.x), f2b = __half22float2(*(__half2*)&q2.y);
        float2 f3a = __half22float2(*(__half2*)&q3.x), f3b = __half22float2(*(__half2*)&q3.y);
        a0 += p0*f0a.x + p1*f1a.x + p2*f2a.x + p3*f3a.x;
        a1 += p0*f0a.y + p1*f1a.y + p2*f2a.y + p3*f3a.y;
        a2 += p0*f0b.x + p1*f1b.x + p2*f2b.x + p3*f3b.x;
        a3 += p0*f0b.y + p1*f1b.y + p2*f2b.y + p3*f3b.y;
    }
    for (; i < end; i += 2) {
        int s = scsr[i];
        float e = as2[s] + adn; e = e > 0.f ? e : 0.2f*e;
        float p = __expf(e);
        psum += p;
        uint2 q = *(const uint2*)(h2h + (size_t)s*C + 4*cl);
        float2 fa = __half22float2(*(__half2*)&q.x), fb = __half22float2(*(__half2*)&q.y);
        a0 += p*fa.x; a1 += p*fa.y; a2 += p*fb.x; a3 += p*fb.y;
    }
    a0 += __shfl_xor(a0, 32); a1 += __shfl_xor(a1, 32);
    a2 += __shfl_xor(a2, 32); a3 += __shfl_xor(a3, 32);
    psum += __shfl_xor(psum, 32);
    float inv = 1.f / (psum + 1e-16f);
    float4 bb = *(const float4*)(b2 + 4*cl);
    float4 wp = *(const float4*)(Wp + 4*cl);
    float v0 = a0*inv + bb.x; v0 = v0 > 0.f ? v0 : 0.f;
    float v1 = a1*inv + bb.y; v1 = v1 > 0.f ? v1 : 0.f;
    float v2 = a2*inv + bb.z; v2 = v2 > 0.f ? v2 : 0.f;
    float v3 = a3*inv + bb.w; v3 = v3 > 0.f ? v3 : 0.f;
    float contrib = v0*wp.x + v1*wp.y + v2*wp.z + v3*wp.w;
    #pragma unroll
    for (int o = 1; o < 32; o <<= 1) contrib += __shfl_xor(contrib, o);
    if (lane == 0) out[n] = contrib + bp[0];
}

// ---------------- host launcher ----------------
extern "C" void kernel_launch(void* const* d_in, const int* in_sizes, int n_in,
                              void* d_out, int out_size, void* d_ws, size_t ws_size,
                              hipStream_t stream)
{
    const float* x    = (const float*)d_in[0];
    const int*   ei   = (const int*)d_in[1];
    const int*   srci = ei;
    const int*   dsti = ei + E_IN;
    const float* W1   = (const float*)d_in[2];
    const float* as1w = (const float*)d_in[3];
    const float* ad1w = (const float*)d_in[4];
    const float* b1   = (const float*)d_in[5];
    const float* W2   = (const float*)d_in[6];
    const float* as2w = (const float*)d_in[7];
    const float* ad2w = (const float*)d_in[8];
    const float* b2   = (const float*)d_in[9];
    const float* Wp   = (const float*)d_in[10];
    const float* bp   = (const float*)d_in[11];
    float* out = (float*)d_out;

    char* ws = (char*)d_ws;
    size_t off = 0;
    auto alloc = [&](size_t bytes) -> char* {
        char* p = ws + off;
        off = (off + bytes + 255) & ~(size_t)255;
        return p;
    };
    float*     a1x    = (float*)alloc((size_t)N_NODES * 8 * 4);
    float4*    ad1v   = (float4*)alloc((size_t)N_NODES * 16);
    float*     wxn    = (float*)alloc((size_t)N_NODES * 8 * 4);
    __half*    h2h    = (__half*)alloc((size_t)N_NODES * C * 2);
    _Float16*  w2h    = (_Float16*)alloc((size_t)F1 * C * 2);
    float*     as2    = (float*)alloc((size_t)N_NODES * 4);
    float*     ad2    = (float*)alloc((size_t)N_NODES * 4);
    int*       deg    = (int*)alloc((size_t)N_NODES * 4);
    int*       offs   = (int*)alloc((size_t)(N_NODES + 1) * 4);
    int*       cursor = (int*)alloc((size_t)N_NODES * 4);
    int*       scsr   = (int*)alloc((size_t)E_TOT * 4);

    const int EB = 256;
    const int egrid = (E_TOT + EB - 1) / EB;

    k_as1z<<<104, 256, 0, stream>>>(x, W1, as1w, ad1w, W2, w2h, a1x, ad1v, deg);
    k_hist<<<egrid, EB, 0, stream>>>(dsti, deg);
    k_scan<<<1, 256, 0, stream>>>(deg, offs, cursor);
    k_scatter<<<egrid, EB, 0, stream>>>(srci, dsti, cursor, scsr);
    k_fused1<<<N_NODES / 16, 256, 0, stream>>>(offs, scsr, a1x, ad1v, wxn);
    k_gemm2<<<(N_NODES/16 + 3) / 4, 256, 0, stream>>>(wxn, W1, b1, w2h, as2w, ad2w,
                                                      h2h, as2, ad2);
    k_agg2<<<N_NODES / 4, 256, 0, stream>>>(offs, scsr, as2, ad2, h2h, b2, Wp, bp, out);
}